// Round 12
// baseline (3107.230 us; speedup 1.0000x reference)
//
#include <hip/hip_runtime.h>
#include <math.h>

// NMSLoss3: sequential greedy-NMS pull/push loss.
// B=2, N=2048 proposals, G=64 gt boxes. Output: 2 floats [push/B, pull/B].
//
// R12 == R11 resubmission (broker timeout; R11 never ran).
// R10 post-mortem (2970us, VGPR_Count=152, FETCH 61->106KB): the compiler
// refused to unroll the 32-word scan loop (convergent ballot/shfl + large
// body), so box_reg[]/aw[] became runtime-indexed -> scratch. Fix:
// macro-expand all 32 words with LITERAL indices and NAMED variables - no
// loop, no array, no unroller decision. ~330 VGPR at 1 wave/SIMD.
//
// Carried structure (R4 measured 3894us bit-exact; R10 measured 2970us
// bit-exact): score-sorted proposals (in-LDS bitonic, u64 keys) so
// selection == first alive in sorted order, found during the scan;
// wave-uniform alive words + __ballot bookkeeping (no per-step reduce
// chains; psum shuffle-reduce only on steps with eligible kills);
// next-selection prefetch mid-scan; rec boxes on lane g via __shfl.
// All IoU arithmetic keeps the exact operand order of the reference
// (IEEE div, (area_a + area_b - inter) + 1e-12, same gating).

#define NMS_THR 0.5f
#define EPS_F 1e-6f
#define NPAD 2048
#define NWORDS 32

__device__ __forceinline__ unsigned long long init_mask(int r, int N) {
    long base = (long)r * 64;
    if (base + 64 <= N) return ~0ULL;
    if (base >= N) return 0ULL;
    return (~0ULL) >> (64 - (int)(N - base));
}

__global__ __launch_bounds__(64, 1) void nms_loss_kernel(
    const int* __restrict__ gt_inds,      // [B, N]
    const float* __restrict__ gt_bboxes,  // [B, G, 4]
    const float* __restrict__ proposals,  // [B, N, 5]
    float* __restrict__ out,              // [2]
    int N, int G, float inv_B)
{
    const int b    = blockIdx.x;
    const int lane = threadIdx.x;   // 0..63

    __shared__ unsigned long long skey[NPAD];   // 16KB; becomes sgg_s after sort
    __shared__ float4 boxes_s[NPAD];            // 32KB (sorted boxes)
    __shared__ float  gtiou[64 * 64];           // 16KB
    float2* sgg_s = reinterpret_cast<float2*>(skey);   // (score, gi bits), sorted

    const int*   gi_b   = gt_inds   + (size_t)b * N;
    const float* prop_b = proposals + (size_t)b * N * 5;
    const float* gtb    = gt_bboxes + (size_t)b * G * 4;

    // ---- build sort keys: ascending sort of ~(score_bits<<32 | ~j)
    //      => descending score, tie -> smaller original j first ----
    for (int j = lane; j < NPAD; j += 64) {
        unsigned long long key;
        if (j < N) {
            float s = prop_b[(size_t)j * 5 + 4];   // scores in (0,1] => bits order-isomorphic
            key = ~(((unsigned long long)__float_as_uint(s) << 32)
                    | (unsigned long long)(0xffffffffu - (unsigned)j));
        } else {
            key = ~0ULL;                            // pads sort to the end
        }
        skey[j] = key;
    }
    __syncthreads();

    // ---- bitonic sort (ascending), single wave, 2048 elements ----
    for (int k = 2; k <= NPAD; k <<= 1) {
        for (int jj = k >> 1; jj > 0; jj >>= 1) {
            for (int t = lane; t < NPAD; t += 64) {
                int l = t ^ jj;
                if (l > t) {
                    unsigned long long a = skey[t], c = skey[l];
                    bool up = ((t & k) == 0);
                    if ((a > c) == up) { skey[t] = c; skey[l] = a; }
                }
            }
            __syncthreads();
        }
    }

    // ---- stage sorted original indices, then overwrite skey with sgg ----
    // low 32 bits of key == original index j (since ~(0xffffffff-j) == j)
    unsigned idxs[NWORDS];
    #pragma unroll
    for (int w = 0; w < NWORDS; ++w) idxs[w] = (unsigned)skey[w * 64 + lane];
    __syncthreads();   // all key reads done before sgg_s overwrites skey

    #pragma unroll
    for (int w = 0; w < NWORDS; ++w) {
        int sp = w * 64 + lane;
        if (sp < N) {
            unsigned idx = idxs[w];
            const float* pr = prop_b + (size_t)idx * 5;
            boxes_s[sp] = make_float4(pr[0], pr[1], pr[2], pr[3]);
            sgg_s[sp]   = make_float2(pr[4], __int_as_float(gi_b[idx]));
        } else {
            boxes_s[sp] = make_float4(0.f, 0.f, 0.f, 0.f);
            sgg_s[sp]   = make_float2(1.0f, __int_as_float(0));
        }
    }

    // ---- gt iou table: gtiou[row*64+col], denom (area_row+area_col)-inter ----
    float4 gb = make_float4(0.f, 0.f, 0.f, 0.f);
    if (lane < G) {
        gb.x = gtb[lane * 4 + 0];
        gb.y = gtb[lane * 4 + 1];
        gb.z = gtb[lane * 4 + 2];
        gb.w = gtb[lane * 4 + 3];
    }
    float area_l = (gb.z - gb.x) * (gb.w - gb.y);
    for (int c = 0; c < G; ++c) {
        float cx1 = __shfl(gb.x, c), cy1 = __shfl(gb.y, c);
        float cx2 = __shfl(gb.z, c), cy2 = __shfl(gb.w, c);
        float area_c = (cx2 - cx1) * (cy2 - cy1);
        float ltx = fmaxf(gb.x, cx1), lty = fmaxf(gb.y, cy1);
        float rbx = fminf(gb.z, cx2), rby = fminf(gb.w, cy2);
        float w = fmaxf(rbx - ltx, 0.0f), h = fmaxf(rby - lty, 0.0f);
        float inter = w * h;
        if (lane < G)
            gtiou[lane * 64 + c] = inter / (area_l + area_c - inter + 1e-12f);
    }
    __syncthreads();

    // ---- NAMED per-word state (literal indices => guaranteed VGPRs) ----
#define DECL_WORD(R) \
    float4 bx_##R = boxes_s[R * 64 + lane]; \
    float  ar_##R = (bx_##R.z - bx_##R.x) * (bx_##R.w - bx_##R.y); \
    float2 sg_##R = sgg_s[R * 64 + lane]; \
    float  sc_##R = sg_##R.x; \
    int    gi_##R = __float_as_int(sg_##R.y); \
    unsigned long long aw_##R = init_mask(R, N);

    DECL_WORD(0)  DECL_WORD(1)  DECL_WORD(2)  DECL_WORD(3)
    DECL_WORD(4)  DECL_WORD(5)  DECL_WORD(6)  DECL_WORD(7)
    DECL_WORD(8)  DECL_WORD(9)  DECL_WORD(10) DECL_WORD(11)
    DECL_WORD(12) DECL_WORD(13) DECL_WORD(14) DECL_WORD(15)
    DECL_WORD(16) DECL_WORD(17) DECL_WORD(18) DECL_WORD(19)
    DECL_WORD(20) DECL_WORD(21) DECL_WORD(22) DECL_WORD(23)
    DECL_WORD(24) DECL_WORD(25) DECL_WORD(26) DECL_WORD(27)
    DECL_WORD(28) DECL_WORD(29) DECL_WORD(30) DECL_WORD(31)
#undef DECL_WORD

    int   alive_count = N;
    int   rec_reg = -1;          // lane g holds sorted position of rec[g] ...
    float rec_x = 0.f, rec_y = 0.f, rec_z = 0.f, rec_w = 0.f, rec_a = 0.f;
    //    ... and its box coords + area (bits identical to boxes_s[rec])
    float pull_s = 0.0f, push_s = 0.0f, pull_c = 0.0f, push_c = 0.0f;

    // first selection = sorted position 0; clear its bit and prefetch.
    int p = (N > 0) ? 0 : -1;
    float4 nbi = make_float4(0.f, 0.f, 0.f, 0.f);
    float2 nsm = make_float2(1.0f, __int_as_float(0));
    if (p == 0) {
        aw_0 &= ~1ULL;
        nbi = boxes_s[0];
        nsm = sgg_s[0];
    }

    for (int step = 0; step < N && p >= 0; ++step) {
        const float4 bi = nbi;                   // prefetched broadcast data
        const float2 sm = nsm;
        const float  si = sm.x;
        const int    g  = __float_as_int(sm.y);
        const float  area_i = (bi.z - bi.x) * (bi.w - bi.y);

        const int  rec_g   = __shfl(rec_reg, g);
        const bool has_rec = rec_g >= 0;

        alive_count -= 1;                        // i removed (bit pre-cleared)
        const bool remaining = alive_count > 0;

        if (has_rec) {
            pull_c += 1.0f;
            if (remaining) {
                // rec box from lane g's registers (5 independent shuffles)
                float brx = __shfl(rec_x, g), bry = __shfl(rec_y, g);
                float brz = __shfl(rec_z, g), brw = __shfl(rec_w, g);
                float area_r = __shfl(rec_a, g);
                float ltx = fmaxf(brx, bi.x), lty = fmaxf(bry, bi.y);
                float rbx = fminf(brz, bi.z), rby = fminf(brw, bi.w);
                float w = fmaxf(rbx - ltx, 0.0f), h = fmaxf(rby - lty, 0.0f);
                float inter = w * h;
                float iou = inter / (area_r + area_i - inter + 1e-12f);
                float msi = fmaxf(iou, EPS_F);
                pull_s += -logf(1.0f - NMS_THR + msi) * si;
            }
        } else {
            if (lane == g) {
                rec_reg = p;
                rec_x = bi.x; rec_y = bi.y; rec_z = bi.z; rec_w = bi.w;
                rec_a = area_i;
            }
        }

        // -- kill scan: 32 macro-expanded words, all state in registers --
        float psum = 0.0f;
        int   pcnt = 0, killed = 0;
        int   next_p = -1;
        const float* __restrict__ gtrow = &gtiou[g * 64];

#define SCAN_WORD(R) \
        if (aw_##R != 0ULL) { \
            float ltx = fmaxf(bi.x, bx_##R.x), lty = fmaxf(bi.y, bx_##R.y); \
            float rbx = fminf(bi.z, bx_##R.z), rby = fminf(bi.w, bx_##R.w); \
            float w = fmaxf(rbx - ltx, 0.0f), h = fmaxf(rby - lty, 0.0f); \
            float inter = w * h; \
            float iou = inter / (area_i + ar_##R - inter + 1e-12f); \
            unsigned long long K = aw_##R & __ballot(iou > NMS_THR); \
            if (K) { \
                aw_##R &= ~K; \
                killed += __popcll(K); \
                unsigned long long E = \
                    K & __ballot((gi_##R != g) && (iou > gtrow[gi_##R])); \
                if (E) { \
                    pcnt += __popcll(E); \
                    bool elig = (E >> lane) & 1ULL; \
                    float pv = (-logf(1.0f + NMS_THR - iou) - logf(sc_##R)) \
                               * sc_##R; \
                    psum += elig ? pv : 0.0f; \
                } \
            } \
            if (next_p < 0 && aw_##R) { \
                int bp = __builtin_ctzll(aw_##R); \
                next_p = R * 64 + bp; \
                aw_##R &= ~(1ULL << bp); \
                nbi = boxes_s[next_p]; \
                nsm = sgg_s[next_p]; \
            } \
        }

        SCAN_WORD(0)  SCAN_WORD(1)  SCAN_WORD(2)  SCAN_WORD(3)
        SCAN_WORD(4)  SCAN_WORD(5)  SCAN_WORD(6)  SCAN_WORD(7)
        SCAN_WORD(8)  SCAN_WORD(9)  SCAN_WORD(10) SCAN_WORD(11)
        SCAN_WORD(12) SCAN_WORD(13) SCAN_WORD(14) SCAN_WORD(15)
        SCAN_WORD(16) SCAN_WORD(17) SCAN_WORD(18) SCAN_WORD(19)
        SCAN_WORD(20) SCAN_WORD(21) SCAN_WORD(22) SCAN_WORD(23)
        SCAN_WORD(24) SCAN_WORD(25) SCAN_WORD(26) SCAN_WORD(27)
        SCAN_WORD(28) SCAN_WORD(29) SCAN_WORD(30) SCAN_WORD(31)
#undef SCAN_WORD

        alive_count -= killed;
        if (pcnt > 0) {                           // rare: reduce only then
            float ps = psum;
            for (int off = 32; off; off >>= 1) ps += __shfl_xor(ps, off);
            push_s += ps / (float)pcnt;
            push_c += (float)pcnt;
        }
        p = next_p;
    }

    // finalize: batch loss, averaged over B (PUSH_W = PULL_W = 1)
    float push_norm = push_s / (push_c + EPS_F);
    float pull_norm = pull_s / (pull_c + EPS_F);
    if (lane == 0) {
        atomicAdd(&out[0], push_norm * inv_B);
        atomicAdd(&out[1], pull_norm * inv_B);
    }
}

extern "C" void kernel_launch(void* const* d_in, const int* in_sizes, int n_in,
                              void* d_out, int out_size, void* d_ws, size_t ws_size,
                              hipStream_t stream) {
    // inputs (setup_inputs order): gt_inds[B,N] i32, anchor_gt_inds[B,N] i32,
    // gt_bboxes[B,G,4] f32, proposal_list[B,N,5] f32
    const int B = 2;
    const int N = in_sizes[1] / B;          // 2048
    const int G = in_sizes[2] / (B * 4);    // 64

    const int*   anchor_gt = (const int*)d_in[1];
    const float* gt_bboxes = (const float*)d_in[2];
    const float* proposals = (const float*)d_in[3];
    float* out = (float*)d_out;

    hipMemsetAsync(out, 0, 2 * sizeof(float), stream);
    nms_loss_kernel<<<B, 64, 0, stream>>>(anchor_gt, gt_bboxes, proposals,
                                          out, N, G, 1.0f / (float)B);
}